// Round 24
// baseline (1521.189 us; speedup 1.0000x reference)
//
#include <hip/hip_runtime.h>

#define HID 512
#define NB  256
#define TT  256
#define DIN 64
#define HBUF 131072                  // shorts per h panel (bf16)
#define SLOT_SH HBUF                 // slot = one panel (256 KB)
#define NSLOT 8                      // rotation depth; fence every NSLOT iters

typedef __attribute__((ext_vector_type(8))) short short8;
typedef __attribute__((ext_vector_type(4))) float f32x4;

__device__ __forceinline__ unsigned short f2bf(float f) {
    unsigned int u = __float_as_uint(f);
    u += 0x7FFF + ((u >> 16) & 1);
    return (unsigned short)(u >> 16);
}
__device__ __forceinline__ float bf2f(unsigned short h) {
    return __uint_as_float(((unsigned int)h) << 16);
}

// fast activations: v_exp_f32 + v_rcp_f32 (error ~1e-6, budget 7.2e-4)
__device__ __forceinline__ float fsig(float x) {
    return __builtin_amdgcn_rcpf(1.f + __expf(-x));
}
__device__ __forceinline__ float ftanh(float x) {
    return 1.f - 2.f * __builtin_amdgcn_rcpf(1.f + __expf(2.f * x));
}

// ---- LLC-coherent (cross-XCD) 4B access, explicit sc0/sc1 cache bits ----
__device__ __forceinline__ void st_u32_llc(unsigned* p, unsigned v) {
    asm volatile("global_store_dword %0, %1, off sc0 sc1" :: "v"(p), "v"(v) : "memory");
}
__device__ __forceinline__ unsigned ld_u32_llc(const unsigned* p) {
    unsigned v;
    asm volatile("global_load_dword %0, %1, off sc0 sc1\n\ts_waitcnt vmcnt(0)"
                 : "=v"(v) : "v"(p) : "memory");
    return v;
}

// single-bf16 weights: one MFMA per operand pair
#define MFMA1(acc, a, b) acc = __builtin_amdgcn_mfma_f32_16x16x32_bf16(a, b, acc, 0, 0, 0)

// LDS (shorts): sW0: 36 frags (18 kt x 2 bf) x 512; sW1: 64 frags x 512
#define SW0_F 36
#define SW1_F 64
#define SW0_N (SW0_F * 512)
#define SW1_N (SW1_F * 512)
#define LDS_BYTES ((SW0_N + SW1_N) * 2)     // 102400

// packed 2-lane h store: lanes (l, l+1) hold adjacent j; even lane stores u32
__device__ __forceinline__ void store_h_pair(unsigned short* buf, size_t hoff,
                                             unsigned short v, int l) {
    unsigned int hv = (unsigned int)v;
    unsigned int up = __shfl_down(hv, 1);
    if ((l & 1) == 0)
        st_u32_llc((unsigned*)(buf + hoff), hv | (up << 16));
}

// wait: 64 lanes poll one flag each (LLC loads), then barrier
__device__ __forceinline__ void flag_wait(unsigned* fset, int target) {
    if (threadIdx.x < 64) {
        unsigned* p = fset + threadIdx.x;
        while ((int)ld_u32_llc(p) < target) __builtin_amdgcn_s_sleep(1);
    }
    __syncthreads();
}

// 4x4 transpose over lane-bits[3:2] <-> register index (4 shfl_xor)
__device__ __forceinline__ void orbit_transpose(f32x4& v, int m) {
    { float a = (m & 1) ? v[0] : v[1]; float b = __shfl_xor(a, 4); if (m & 1) v[0] = b; else v[1] = b; }
    { float a = (m & 1) ? v[2] : v[3]; float b = __shfl_xor(a, 4); if (m & 1) v[2] = b; else v[3] = b; }
    { float a = (m & 2) ? v[0] : v[2]; float b = __shfl_xor(a, 8); if (m & 2) v[0] = b; else v[2] = b; }
    { float a = (m & 2) ? v[1] : v[3]; float b = __shfl_xor(a, 8); if (m & 2) v[1] = b; else v[3] = b; }
}

__global__ __launch_bounds__(512, 2) void lstm_persistent(
    const float* __restrict__ x,
    const float* __restrict__ Wih0, const float* __restrict__ Whh0,
    const float* __restrict__ bih0, const float* __restrict__ bhh0,
    const float* __restrict__ Wih1, const float* __restrict__ Whh1,
    const float* __restrict__ bih1, const float* __restrict__ bhh1,
    const float* __restrict__ headw, const float* __restrict__ headb,
    unsigned short* h0base, unsigned short* h1base,
    unsigned* gf, float* __restrict__ out)
{
    extern __shared__ unsigned short lds[];
    unsigned short* sW0 = lds;                 // [36 frags][512]
    unsigned short* sW1 = lds + SW0_N;         // [64 frags][512]

    const int tid = threadIdx.x;
    const int l   = tid & 63;
    const int w   = tid >> 6;         // wave 0..7
    const int bt  = w >> 1;           // batch tile 0..3 (16 rows each)
    const int bf  = w & 1;            // j-half of the block's 8 j's
    const int bid = blockIdx.x;
    const int gq  = bid & 3;          // batch group (64 rows)
    const int jb  = bid >> 2;         // j-block 0..63 (hidden units jb*8..jb*8+7)

    unsigned* f0g = gf + gq * 64;            // layer0-done flags (this group)
    unsigned* f1g = gf + 256 + gq * 64;      // layer1-done flags (this group)

    // ---- weight preload: fp32 -> single bf16 fragments in LDS ----
    const int r16 = l & 15;
    const int ko  = (l >> 4) * 8;
    {
        const int nrow = (r16 >> 2) * HID + jb * 8 + (r16 & 3);   // + bf_*4 added per frag
        for (int fi = w; fi < SW0_F; fi += 8) {
            const int kt = fi >> 1, bf_ = fi & 1;
            const int n = nrow + bf_ * 4;
            const float* src = (kt < 2) ? (Wih0 + (size_t)n * DIN + kt * 32 + ko)
                                        : (Whh0 + (size_t)n * HID + (kt - 2) * 32 + ko);
            float v[8];
            *(float4*)&v[0] = *(const float4*)src;
            *(float4*)&v[4] = *(const float4*)(src + 4);
            union { unsigned short u[8]; uint4 q; } pb;
            #pragma unroll
            for (int e = 0; e < 8; ++e) pb.u[e] = f2bf(v[e]);
            *(uint4*)&sW0[fi * 512 + l * 8] = pb.q;
        }
        for (int fi = w; fi < SW1_F; fi += 8) {
            const int kt = fi >> 1, bf_ = fi & 1;
            const int n = nrow + bf_ * 4;
            const float* src = (kt < 16) ? (Wih1 + (size_t)n * HID + kt * 32 + ko)
                                         : (Whh1 + (size_t)n * HID + (kt - 16) * 32 + ko);
            float v[8];
            *(float4*)&v[0] = *(const float4*)src;
            *(float4*)&v[4] = *(const float4*)(src + 4);
            union { unsigned short u[8]; uint4 q; } pb;
            #pragma unroll
            for (int e = 0; e < 8; ++e) pb.u[e] = f2bf(v[e]);
            *(uint4*)&sW1[fi * 512 + l * 8] = pb.q;
        }
    }

    float bias0[4], bias1[4];
    #pragma unroll
    for (int gi = 0; gi < 4; ++gi) {
        const int nn = gi * HID + jb * 8 + bf * 4 + (l & 3);
        bias0[gi] = bih0[nn] + bhh0[nn];
        bias1[gi] = bih1[nn] + bhh1[nn];
    }
    float c0 = 0.f, c1 = 0.f;

    // epilogue geometry after orbit transpose: lane owns
    //   b_in = (l>>4)*4 + ((l>>2)&3), j = l&3 (within this wave's 4 j's)
    const int m      = (l >> 2) & 3;
    const int b_in   = (l >> 4) * 4 + m;
    const int b_glob = gq * 64 + bt * 16 + b_in;
    const int j_glob = jb * 8 + bf * 4 + (l & 3);
    const size_t hoff = ((((size_t)(b_glob >> 4)) * 16 + (j_glob >> 5)) * 64
                         + ((b_glob & 15) | (((j_glob >> 3) & 3) << 4))) * 8 + (j_glob & 7);
    const int btg = gq * 4 + bt;     // global batch tile (0..15)

    // x prefetch registers
    const int xrow = gq * 64 + bt * 16 + (l & 15);
    float xv0[8], xv1[8];
    {
        const float* s0 = x + ((size_t)xrow * TT + 0) * DIN + ko;
        *(float4*)&xv0[0] = *(const float4*)s0;
        *(float4*)&xv0[4] = *(const float4*)(s0 + 4);
        *(float4*)&xv1[0] = *(const float4*)(s0 + 32);
        *(float4*)&xv1[4] = *(const float4*)(s0 + 36);
    }

    __syncthreads();                 // weights ready

    // x-part B fragments pinned in VGPRs (kt = 0,1; own bf)
    const short8 bx0 = *(const short8*)&sW0[(0 * 2 + bf) * 512 + l * 8];
    const short8 bx1 = *(const short8*)&sW0[(1 * 2 + bf) * 512 + l * 8];

    // speculative h0 A-fragment prefetch state (per-wave)
    short8 pAh[16];
    bool hitA = false;

    for (int it = 0; it <= TT; ++it) {
        // ---- wait 1: layer0 of it-1 done everywhere. Skip spin if this wave
        // ---- already CONFIRMED the flags at prefetch time (monotone flags).
        if (!hitA && tid < 64) {
            unsigned* p = f0g + tid;
            while ((int)ld_u32_llc(p) < it) __builtin_amdgcn_s_sleep(1);
        }
        __syncthreads();

        // slot map: h0[t] -> slot t&7 ; h1[t] -> slot t&7
        const unsigned short* h0c = h0base + (size_t)((it + 7) & 7) * SLOT_SH;  // h0[it-1]
        unsigned short* h0n       = h0base + (size_t)(it & 7) * SLOT_SH;        // h0[it]
        const unsigned short* h1c = h1base + (size_t)((it + 6) & 7) * SLOT_SH;  // h1[it-2]
        unsigned short* h1n       = h1base + (size_t)((it + 7) & 7) * SLOT_SH;  // h1[it-1]

        f32x4 acc0[2] = {{0.f,0.f,0.f,0.f},{0.f,0.f,0.f,0.f}};
        f32x4 acc1[2] = {{0.f,0.f,0.f,0.f},{0.f,0.f,0.f,0.f}};

        // ---- h0[it-1] A-fragments: prefetched at bottom of it-1 (common), else
        // ---- 16 b128 loads batched now. Used by layer0 AND layer1 ys0-part.
        if (!hitA) {
            #pragma unroll
            for (int kt = 0; kt < 16; ++kt) {
                const size_t o = (((size_t)btg * 16 + kt) * 64 + l) * 8;
                pAh[kt] = *(const short8*)&h0c[o];
            }
        }

        // ================= layer 0, t = it =================
        if (it < TT) {
            // x part: hi/lo input x single-bf16 W (pinned regs)
            {
                union { unsigned short u[8]; short8 s; } ah, al;
                #pragma unroll
                for (int e = 0; e < 8; ++e) {
                    unsigned short h = f2bf(xv0[e]);
                    ah.u[e] = h; al.u[e] = f2bf(xv0[e] - bf2f(h));
                }
                MFMA1(acc0[0], ah.s, bx0);
                MFMA1(acc0[0], al.s, bx0);
                #pragma unroll
                for (int e = 0; e < 8; ++e) {
                    unsigned short h = f2bf(xv1[e]);
                    ah.u[e] = h; al.u[e] = f2bf(xv1[e] - bf2f(h));
                }
                MFMA1(acc0[1], ah.s, bx1);
                MFMA1(acc0[1], al.s, bx1);
            }
            #pragma unroll
            for (int kt = 0; kt < 16; ++kt) {
                short8 b = *(const short8*)&sW0[((kt + 2) * 2 + bf) * 512 + l * 8];
                MFMA1(acc0[kt & 1], pAh[kt], b);
            }
            // ---- wave-local epilogue: orbit transpose -> gates in-lane
            {
                f32x4 v = acc0[0] + acc0[1];
                orbit_transpose(v, m);
                const float iG = fsig(v[0] + bias0[0]);
                const float fG = fsig(v[1] + bias0[1]);
                const float gT = ftanh(v[2] + bias0[2]);
                const float oG = fsig(v[3] + bias0[3]);
                c0 = fmaf(fG, c0, iG * gT);
                const float h = oG * ftanh(c0);
                store_h_pair(h0n, hoff, f2bf(h), l);
            }
            // ---- EARLY layer0-done signal: unblocks next iteration's wait-1
            asm volatile("s_waitcnt vmcnt(0)" ::: "memory");
            __syncthreads();
            if (tid == 0) st_u32_llc(f0g + jb, (unsigned)(it + 1));
        }

        // prefetch x[it+1]
        if (it + 1 < TT) {
            const float* s0 = x + ((size_t)xrow * TT + (it + 1)) * DIN + ko;
            *(float4*)&xv0[0] = *(const float4*)s0;
            *(float4*)&xv0[4] = *(const float4*)(s0 + 4);
            *(float4*)&xv1[0] = *(const float4*)(s0 + 32);
            *(float4*)&xv1[4] = *(const float4*)(s0 + 36);
        }

        // ---- ys0-part of layer1: needs only pAh (guarded by wait-1) + static sW1.
        if (it > 0) {
            #pragma unroll
            for (int kt = 0; kt < 16; ++kt) {
                short8 b = *(const short8*)&sW1[(kt * 2 + bf) * 512 + l * 8];
                MFMA1(acc1[kt & 1], pAh[kt], b);
            }
        }

        // ---- wait 2: layer1 of it-1 done everywhere (covers h1[it-2] writes)
        flag_wait(f1g, it);

        // ================= layer 1 (h1 half), t = it-1 =================
        if (it > 0) {
            short8 fCh[16];
            #pragma unroll
            for (int kt = 0; kt < 16; ++kt) {
                const size_t o = (((size_t)btg * 16 + kt) * 64 + l) * 8;
                fCh[kt] = *(const short8*)&h1c[o];
            }
            #pragma unroll
            for (int kt = 0; kt < 16; ++kt) {
                short8 b = *(const short8*)&sW1[((16 + kt) * 2 + bf) * 512 + l * 8];
                MFMA1(acc1[kt & 1], fCh[kt], b);
            }
            {
                f32x4 v = acc1[0] + acc1[1];
                orbit_transpose(v, m);
                const float iG = fsig(v[0] + bias1[0]);
                const float fG = fsig(v[1] + bias1[1]);
                const float gT = ftanh(v[2] + bias1[2]);
                const float oG = fsig(v[3] + bias1[3]);
                c1 = fmaf(fG, c1, iG * gT);
                const float h = oG * ftanh(c1);
                store_h_pair(h1n, hoff, f2bf(h), l);
            }
        }
        // ---- layer1-done signal + windowed fence (1/NSLOT iters, non-polling wave)
        asm volatile("s_waitcnt vmcnt(0)" ::: "memory");
        __syncthreads();
        if (tid == 0) st_u32_llc(f1g + jb, (unsigned)(it + 1));
        if ((it & 7) == 7 && tid >= 448)
            __builtin_amdgcn_fence(__ATOMIC_ACQUIRE, "agent");

        // ---- speculative prefetch for it+1 (AFTER fence block, preserving the
        // ---- slot-staleness invariant): confirm f0 >= it+1 at LLC, THEN issue
        // ---- the 16 fragment loads so their latency hides under loop-back.
        hitA = false;
        if (it < TT) {
            unsigned fv = ld_u32_llc(f0g + l);      // lane l checks flag l (all waves)
            hitA = __all((int)fv >= it + 1);
            if (hitA) {
                const unsigned short* nsrc = h0base + (size_t)(it & 7) * SLOT_SH;  // h0[it]
                #pragma unroll
                for (int kt = 0; kt < 16; ++kt) {
                    const size_t o = (((size_t)btg * 16 + kt) * 64 + l) * 8;
                    pAh[kt] = *(const short8*)&nsrc[o];
                }
            }
        }
    }

    // ---- head: out[b] = h1[TT-1] . w + b (slot 7; all layer1 done first)
    if (jb == 0) {
        if (tid < 64) {
            unsigned* p = f1g + tid;
            while ((int)ld_u32_llc(p) < TT + 1) __builtin_amdgcn_s_sleep(1);
        }
        __syncthreads();
        const unsigned short* h1h = h1base + (size_t)((TT + 7) & 7) * SLOT_SH;
        const int bl_ = tid >> 3;            // 0..63 within group
        const int qd  = tid & 7;
        const int b   = gq * 64 + bl_;
        const int btw = b >> 4;
        float s = 0.f;
        #pragma unroll
        for (int jt = qd * 2; jt < qd * 2 + 2; ++jt) {
            #pragma unroll
            for (int q2 = 0; q2 < 4; ++q2) {
                const size_t off = (((size_t)btw * 16 + jt) * 64 + ((b & 15) | (q2 << 4))) * 8;
                short8 vh = *(const short8*)&h1h[off];
                const int j0 = jt * 32 + q2 * 8;
                #pragma unroll
                for (int e = 0; e < 8; ++e)
                    s += bf2f((unsigned short)vh[e]) * headw[j0 + e];
            }
        }
        s += __shfl_down(s, 4, 8);
        s += __shfl_down(s, 2, 8);
        s += __shfl_down(s, 1, 8);
        if (qd == 0) out[b] = s + headb[0];
    }
}

extern "C" void kernel_launch(void* const* d_in, const int* in_sizes, int n_in,
                              void* d_out, int out_size, void* d_ws, size_t ws_size,
                              hipStream_t stream) {
    const float* x      = (const float*)d_in[0];
    const float* W_ih0  = (const float*)d_in[1];
    const float* W_hh0  = (const float*)d_in[2];
    const float* b_ih0  = (const float*)d_in[3];
    const float* b_hh0  = (const float*)d_in[4];
    const float* W_ih1  = (const float*)d_in[5];
    const float* W_hh1  = (const float*)d_in[6];
    const float* b_ih1  = (const float*)d_in[7];
    const float* b_hh1  = (const float*)d_in[8];
    const float* head_w = (const float*)d_in[9];
    const float* head_b = (const float*)d_in[10];
    float* out = (float*)d_out;

    // ws layout: [flags 4KB (f0 4x64 | f1 4x64)][pad to 1MB][h0: 8x256KB][h1: 8x256KB]
    const size_t SLOT_BYTES = (size_t)SLOT_SH * 2;          // 256 KB
    unsigned* gf = (unsigned*)d_ws;
    unsigned short* h0base = (unsigned short*)((char*)d_ws + (1 << 20));
    unsigned short* h1base = (unsigned short*)((char*)d_ws + (1 << 20) + NSLOT * SLOT_BYTES);

    // zero: flags + the t=-1 slots (slot 7 of each chain)
    hipMemsetAsync(d_ws, 0, 4096, stream);
    hipMemsetAsync((char*)h0base + 7 * SLOT_BYTES, 0, SLOT_BYTES, stream);
    hipMemsetAsync((char*)h1base + 7 * SLOT_BYTES, 0, SLOT_BYTES, stream);

    hipFuncSetAttribute((const void*)lstm_persistent,
                        hipFuncAttributeMaxDynamicSharedMemorySize, LDS_BYTES);
    lstm_persistent<<<dim3(256), dim3(512), LDS_BYTES, stream>>>(
        x, W_ih0, W_hh0, b_ih0, b_hh0, W_ih1, W_hh1, b_ih1, b_hh1,
        head_w, head_b, h0base, h1base, gf, out);
}

// Round 25
// 1449.144 us; speedup vs baseline: 1.0497x; 1.0497x over previous
//
#include <hip/hip_runtime.h>

#define HID 512
#define NB  256
#define TT  256
#define DIN 64
#define HBUF 131072                  // shorts per h panel (bf16)
#define SLOT_SH HBUF                 // slot = one panel (256 KB)
#define NSLOT 8                      // rotation depth; fence every NSLOT iters

typedef __attribute__((ext_vector_type(8))) short short8;
typedef __attribute__((ext_vector_type(4))) float f32x4;

__device__ __forceinline__ unsigned short f2bf(float f) {
    unsigned int u = __float_as_uint(f);
    u += 0x7FFF + ((u >> 16) & 1);
    return (unsigned short)(u >> 16);
}
__device__ __forceinline__ float bf2f(unsigned short h) {
    return __uint_as_float(((unsigned int)h) << 16);
}

// fast activations: v_exp_f32 + v_rcp_f32 (error ~1e-6, budget 7.2e-4)
__device__ __forceinline__ float fsig(float x) {
    return __builtin_amdgcn_rcpf(1.f + __expf(-x));
}
__device__ __forceinline__ float ftanh(float x) {
    return 1.f - 2.f * __builtin_amdgcn_rcpf(1.f + __expf(2.f * x));
}

// ---- LLC-coherent (cross-XCD) 4B access, explicit sc0/sc1 cache bits ----
__device__ __forceinline__ void st_u32_llc(unsigned* p, unsigned v) {
    asm volatile("global_store_dword %0, %1, off sc0 sc1" :: "v"(p), "v"(v) : "memory");
}
__device__ __forceinline__ unsigned ld_u32_llc(const unsigned* p) {
    unsigned v;
    asm volatile("global_load_dword %0, %1, off sc0 sc1\n\ts_waitcnt vmcnt(0)"
                 : "=v"(v) : "v"(p) : "memory");
    return v;
}

// single-bf16 weights: one MFMA per operand pair
#define MFMA1(acc, a, b) acc = __builtin_amdgcn_mfma_f32_16x16x32_bf16(a, b, acc, 0, 0, 0)

// LDS (shorts): sW0: 36 frags (18 kt x 2 bf) x 512; sW1: 64 frags x 512
#define SW0_F 36
#define SW1_F 64
#define SW0_N (SW0_F * 512)
#define SW1_N (SW1_F * 512)
#define LDS_BYTES ((SW0_N + SW1_N) * 2)     // 102400

// packed 2-lane h store: lanes (l, l+1) hold adjacent j; even lane stores u32
__device__ __forceinline__ void store_h_pair(unsigned short* buf, size_t hoff,
                                             unsigned short v, int l) {
    unsigned int hv = (unsigned int)v;
    unsigned int up = __shfl_down(hv, 1);
    if ((l & 1) == 0)
        st_u32_llc((unsigned*)(buf + hoff), hv | (up << 16));
}

// wait: 64 lanes poll one flag each (LLC loads), then barrier
__device__ __forceinline__ void flag_wait(unsigned* fset, int target) {
    if (threadIdx.x < 64) {
        unsigned* p = fset + threadIdx.x;
        while ((int)ld_u32_llc(p) < target) __builtin_amdgcn_s_sleep(1);
    }
    __syncthreads();
}

// 4x4 transpose over lane-bits[3:2] <-> register index (4 shfl_xor)
__device__ __forceinline__ void orbit_transpose(f32x4& v, int m) {
    { float a = (m & 1) ? v[0] : v[1]; float b = __shfl_xor(a, 4); if (m & 1) v[0] = b; else v[1] = b; }
    { float a = (m & 1) ? v[2] : v[3]; float b = __shfl_xor(a, 4); if (m & 1) v[2] = b; else v[3] = b; }
    { float a = (m & 2) ? v[0] : v[2]; float b = __shfl_xor(a, 8); if (m & 2) v[0] = b; else v[2] = b; }
    { float a = (m & 2) ? v[1] : v[3]; float b = __shfl_xor(a, 8); if (m & 2) v[1] = b; else v[3] = b; }
}

__global__ __launch_bounds__(512, 2) void lstm_persistent(
    const float* __restrict__ x,
    const float* __restrict__ Wih0, const float* __restrict__ Whh0,
    const float* __restrict__ bih0, const float* __restrict__ bhh0,
    const float* __restrict__ Wih1, const float* __restrict__ Whh1,
    const float* __restrict__ bih1, const float* __restrict__ bhh1,
    const float* __restrict__ headw, const float* __restrict__ headb,
    unsigned short* h0base, unsigned short* h1base,
    unsigned* gf, float* __restrict__ out)
{
    extern __shared__ unsigned short lds[];
    unsigned short* sW0 = lds;                 // [36 frags][512]
    unsigned short* sW1 = lds + SW0_N;         // [64 frags][512]

    const int tid = threadIdx.x;
    const int l   = tid & 63;
    const int w   = tid >> 6;         // wave 0..7
    const int bt  = w >> 1;           // batch tile 0..3 (16 rows each)
    const int bf  = w & 1;            // j-half of the block's 8 j's
    const int bid = blockIdx.x;
    const int gq  = bid & 3;          // batch group (64 rows)
    const int jb  = bid >> 2;         // j-block 0..63 (hidden units jb*8..jb*8+7)

    unsigned* f0g = gf + gq * 64;            // layer0-done flags (this group)
    unsigned* f1g = gf + 256 + gq * 64;      // layer1-done flags (this group)

    // ---- weight preload: fp32 -> single bf16 fragments in LDS ----
    const int r16 = l & 15;
    const int ko  = (l >> 4) * 8;
    {
        const int nrow = (r16 >> 2) * HID + jb * 8 + (r16 & 3);   // + bf_*4 added per frag
        for (int fi = w; fi < SW0_F; fi += 8) {
            const int kt = fi >> 1, bf_ = fi & 1;
            const int n = nrow + bf_ * 4;
            const float* src = (kt < 2) ? (Wih0 + (size_t)n * DIN + kt * 32 + ko)
                                        : (Whh0 + (size_t)n * HID + (kt - 2) * 32 + ko);
            float v[8];
            *(float4*)&v[0] = *(const float4*)src;
            *(float4*)&v[4] = *(const float4*)(src + 4);
            union { unsigned short u[8]; uint4 q; } pb;
            #pragma unroll
            for (int e = 0; e < 8; ++e) pb.u[e] = f2bf(v[e]);
            *(uint4*)&sW0[fi * 512 + l * 8] = pb.q;
        }
        for (int fi = w; fi < SW1_F; fi += 8) {
            const int kt = fi >> 1, bf_ = fi & 1;
            const int n = nrow + bf_ * 4;
            const float* src = (kt < 16) ? (Wih1 + (size_t)n * HID + kt * 32 + ko)
                                         : (Whh1 + (size_t)n * HID + (kt - 16) * 32 + ko);
            float v[8];
            *(float4*)&v[0] = *(const float4*)src;
            *(float4*)&v[4] = *(const float4*)(src + 4);
            union { unsigned short u[8]; uint4 q; } pb;
            #pragma unroll
            for (int e = 0; e < 8; ++e) pb.u[e] = f2bf(v[e]);
            *(uint4*)&sW1[fi * 512 + l * 8] = pb.q;
        }
    }

    float bias0[4], bias1[4];
    #pragma unroll
    for (int gi = 0; gi < 4; ++gi) {
        const int nn = gi * HID + jb * 8 + bf * 4 + (l & 3);
        bias0[gi] = bih0[nn] + bhh0[nn];
        bias1[gi] = bih1[nn] + bhh1[nn];
    }
    float c0 = 0.f, c1 = 0.f;

    // epilogue geometry after orbit transpose: lane owns
    //   b_in = (l>>4)*4 + ((l>>2)&3), j = l&3 (within this wave's 4 j's)
    const int m      = (l >> 2) & 3;
    const int b_in   = (l >> 4) * 4 + m;
    const int b_glob = gq * 64 + bt * 16 + b_in;
    const int j_glob = jb * 8 + bf * 4 + (l & 3);
    const size_t hoff = ((((size_t)(b_glob >> 4)) * 16 + (j_glob >> 5)) * 64
                         + ((b_glob & 15) | (((j_glob >> 3) & 3) << 4))) * 8 + (j_glob & 7);
    const int btg = gq * 4 + bt;     // global batch tile (0..15)

    // x prefetch registers
    const int xrow = gq * 64 + bt * 16 + (l & 15);
    float xv0[8], xv1[8];
    {
        const float* s0 = x + ((size_t)xrow * TT + 0) * DIN + ko;
        *(float4*)&xv0[0] = *(const float4*)s0;
        *(float4*)&xv0[4] = *(const float4*)(s0 + 4);
        *(float4*)&xv1[0] = *(const float4*)(s0 + 32);
        *(float4*)&xv1[4] = *(const float4*)(s0 + 36);
    }

    __syncthreads();                 // weights ready

    // x-part B fragments pinned in VGPRs (kt = 0,1; own bf)
    const short8 bx0 = *(const short8*)&sW0[(0 * 2 + bf) * 512 + l * 8];
    const short8 bx1 = *(const short8*)&sW0[(1 * 2 + bf) * 512 + l * 8];

    for (int it = 0; it <= TT; ++it) {
        // ---- wait 1: layer0 of it-1 done everywhere (signaled MID-iteration -> fast)
        flag_wait(f0g, it);

        // slot map: h0[t] -> slot t&7 ; h1[t] -> slot t&7
        const unsigned short* h0c = h0base + (size_t)((it + 7) & 7) * SLOT_SH;  // h0[it-1]
        unsigned short* h0n       = h0base + (size_t)(it & 7) * SLOT_SH;        // h0[it]
        const unsigned short* h1c = h1base + (size_t)((it + 6) & 7) * SLOT_SH;  // h1[it-2]
        unsigned short* h1n       = h1base + (size_t)((it + 7) & 7) * SLOT_SH;  // h1[it-1]

        f32x4 acc0[2] = {{0.f,0.f,0.f,0.f},{0.f,0.f,0.f,0.f}};
        f32x4 acc1[2] = {{0.f,0.f,0.f,0.f},{0.f,0.f,0.f,0.f}};

        // ---- hoisted h0[it-1] A-fragments (bf16): 16 b128 loads batched (MLP),
        // ---- used by layer0 (W0hh) AND layer1 ys0-part (W1ih)
        short8 fAh[16];
        #pragma unroll
        for (int kt = 0; kt < 16; ++kt) {
            const size_t o = (((size_t)btg * 16 + kt) * 64 + l) * 8;
            fAh[kt] = *(const short8*)&h0c[o];
        }

        // ================= layer 0, t = it =================
        if (it < TT) {
            // x part: hi/lo input x single-bf16 W (pinned regs)
            {
                union { unsigned short u[8]; short8 s; } ah, al;
                #pragma unroll
                for (int e = 0; e < 8; ++e) {
                    unsigned short h = f2bf(xv0[e]);
                    ah.u[e] = h; al.u[e] = f2bf(xv0[e] - bf2f(h));
                }
                MFMA1(acc0[0], ah.s, bx0);
                MFMA1(acc0[0], al.s, bx0);
                #pragma unroll
                for (int e = 0; e < 8; ++e) {
                    unsigned short h = f2bf(xv1[e]);
                    ah.u[e] = h; al.u[e] = f2bf(xv1[e] - bf2f(h));
                }
                MFMA1(acc0[1], ah.s, bx1);
                MFMA1(acc0[1], al.s, bx1);
            }
            #pragma unroll
            for (int kt = 0; kt < 16; ++kt) {
                short8 b = *(const short8*)&sW0[((kt + 2) * 2 + bf) * 512 + l * 8];
                MFMA1(acc0[kt & 1], fAh[kt], b);
            }
            // ---- wave-local epilogue: orbit transpose -> gates in-lane
            {
                f32x4 v = acc0[0] + acc0[1];
                orbit_transpose(v, m);
                const float iG = fsig(v[0] + bias0[0]);
                const float fG = fsig(v[1] + bias0[1]);
                const float gT = ftanh(v[2] + bias0[2]);
                const float oG = fsig(v[3] + bias0[3]);
                c0 = fmaf(fG, c0, iG * gT);
                const float h = oG * ftanh(c0);
                store_h_pair(h0n, hoff, f2bf(h), l);
            }
            // ---- EARLY layer0-done signal: unblocks next iteration's wait-1
            asm volatile("s_waitcnt vmcnt(0)" ::: "memory");
            __syncthreads();
            if (tid == 0) st_u32_llc(f0g + jb, (unsigned)(it + 1));
        }

        // prefetch x[it+1]
        if (it + 1 < TT) {
            const float* s0 = x + ((size_t)xrow * TT + (it + 1)) * DIN + ko;
            *(float4*)&xv0[0] = *(const float4*)s0;
            *(float4*)&xv0[4] = *(const float4*)(s0 + 4);
            *(float4*)&xv1[0] = *(const float4*)(s0 + 32);
            *(float4*)&xv1[4] = *(const float4*)(s0 + 36);
        }

        // ---- ys0-part of layer1: needs only fAh (guarded by wait-1) + static sW1.
        if (it > 0) {
            #pragma unroll
            for (int kt = 0; kt < 16; ++kt) {
                short8 b = *(const short8*)&sW1[(kt * 2 + bf) * 512 + l * 8];
                MFMA1(acc1[kt & 1], fAh[kt], b);
            }
        }

        // ---- wait 2: layer1 of it-1 done everywhere (covers h1[it-2] writes)
        flag_wait(f1g, it);

        // ================= layer 1 (h1 half), t = it-1 =================
        if (it > 0) {
            short8 fCh[16];
            #pragma unroll
            for (int kt = 0; kt < 16; ++kt) {
                const size_t o = (((size_t)btg * 16 + kt) * 64 + l) * 8;
                fCh[kt] = *(const short8*)&h1c[o];
            }
            #pragma unroll
            for (int kt = 0; kt < 16; ++kt) {
                short8 b = *(const short8*)&sW1[((16 + kt) * 2 + bf) * 512 + l * 8];
                MFMA1(acc1[kt & 1], fCh[kt], b);
            }
            {
                f32x4 v = acc1[0] + acc1[1];
                orbit_transpose(v, m);
                const float iG = fsig(v[0] + bias1[0]);
                const float fG = fsig(v[1] + bias1[1]);
                const float gT = ftanh(v[2] + bias1[2]);
                const float oG = fsig(v[3] + bias1[3]);
                c1 = fmaf(fG, c1, iG * gT);
                const float h = oG * ftanh(c1);
                store_h_pair(h1n, hoff, f2bf(h), l);
            }
        }
        // ---- layer1-done signal + windowed fence (1/NSLOT iters, non-polling wave)
        asm volatile("s_waitcnt vmcnt(0)" ::: "memory");
        __syncthreads();
        if (tid == 0) st_u32_llc(f1g + jb, (unsigned)(it + 1));
        if ((it & 7) == 7 && tid >= 448)
            __builtin_amdgcn_fence(__ATOMIC_ACQUIRE, "agent");
    }

    // ---- head: out[b] = h1[TT-1] . w + b (slot 7; all layer1 done first)
    if (jb == 0) {
        if (tid < 64) {
            unsigned* p = f1g + tid;
            while ((int)ld_u32_llc(p) < TT + 1) __builtin_amdgcn_s_sleep(1);
        }
        __syncthreads();
        const unsigned short* h1h = h1base + (size_t)((TT + 7) & 7) * SLOT_SH;
        const int bl_ = tid >> 3;            // 0..63 within group
        const int qd  = tid & 7;
        const int b   = gq * 64 + bl_;
        const int btw = b >> 4;
        float s = 0.f;
        #pragma unroll
        for (int jt = qd * 2; jt < qd * 2 + 2; ++jt) {
            #pragma unroll
            for (int q2 = 0; q2 < 4; ++q2) {
                const size_t off = (((size_t)btw * 16 + jt) * 64 + ((b & 15) | (q2 << 4))) * 8;
                short8 vh = *(const short8*)&h1h[off];
                const int j0 = jt * 32 + q2 * 8;
                #pragma unroll
                for (int e = 0; e < 8; ++e)
                    s += bf2f((unsigned short)vh[e]) * headw[j0 + e];
            }
        }
        s += __shfl_down(s, 4, 8);
        s += __shfl_down(s, 2, 8);
        s += __shfl_down(s, 1, 8);
        if (qd == 0) out[b] = s + headb[0];
    }
}

extern "C" void kernel_launch(void* const* d_in, const int* in_sizes, int n_in,
                              void* d_out, int out_size, void* d_ws, size_t ws_size,
                              hipStream_t stream) {
    const float* x      = (const float*)d_in[0];
    const float* W_ih0  = (const float*)d_in[1];
    const float* W_hh0  = (const float*)d_in[2];
    const float* b_ih0  = (const float*)d_in[3];
    const float* b_hh0  = (const float*)d_in[4];
    const float* W_ih1  = (const float*)d_in[5];
    const float* W_hh1  = (const float*)d_in[6];
    const float* b_ih1  = (const float*)d_in[7];
    const float* b_hh1  = (const float*)d_in[8];
    const float* head_w = (const float*)d_in[9];
    const float* head_b = (const float*)d_in[10];
    float* out = (float*)d_out;

    // ws layout: [flags 4KB (f0 4x64 | f1 4x64)][pad to 1MB][h0: 8x256KB][h1: 8x256KB]
    const size_t SLOT_BYTES = (size_t)SLOT_SH * 2;          // 256 KB
    unsigned* gf = (unsigned*)d_ws;
    unsigned short* h0base = (unsigned short*)((char*)d_ws + (1 << 20));
    unsigned short* h1base = (unsigned short*)((char*)d_ws + (1 << 20) + NSLOT * SLOT_BYTES);

    // zero: flags + the t=-1 slots (slot 7 of each chain)
    hipMemsetAsync(d_ws, 0, 4096, stream);
    hipMemsetAsync((char*)h0base + 7 * SLOT_BYTES, 0, SLOT_BYTES, stream);
    hipMemsetAsync((char*)h1base + 7 * SLOT_BYTES, 0, SLOT_BYTES, stream);

    hipFuncSetAttribute((const void*)lstm_persistent,
                        hipFuncAttributeMaxDynamicSharedMemorySize, LDS_BYTES);
    lstm_persistent<<<dim3(256), dim3(512), LDS_BYTES, stream>>>(
        x, W_ih0, W_hh0, b_ih0, b_hh0, W_ih1, W_hh1, b_ih1, b_hh1,
        head_w, head_b, h0base, h1base, gf, out);
}